// Round 17
// baseline (688.408 us; speedup 1.0000x reference)
//
#include <hip/hip_runtime.h>
#include <hip/hip_bf16.h>

// Ternary-quantized linear: out[M,N] = x[M,K] . W^T,  W[n,k] = q[n,k]*scale[n].
// R17: R16 (32x32x16 MFMA, BK=128 dbuf, vmcnt(10), 2 raw barriers) with
//      2Mx2N wave layout (wave tile 64x128): A LDS duplication 4x->2x
//      (A reads 32->16 b128/wave-kt; LDS pipe was ~60-68% busy, the
//      co-bottleneck), B reads paired as ds_read_b64 via pre-pass image
//      [ks][g][l31][p] (one b64 = both 32-col fragments of a 64-col group).
//      Cost: 2x unpack VALU (had headroom). acc[2][4]=128 AGPR, same
//      occupancy. Pre-pass: x->bf16 + B k-major paired image. Fallback = R5.

#define M_DIM 8192
#define N_DIM 11008
#define K_DIM 4096
#define BM 128
#define BN 256
#define KT32 32                     // K-tiles of 128
#define NB_N 43
#define NWG 2752                    // 64*43, %8 == 0

#define XBF_BYTES ((size_t)M_DIM * K_DIM * 2)        // 67108864
#define BT_BYTES  ((size_t)N_DIM * K_DIM / 4)        // 11272192
#define WS_NEED   (XBF_BYTES + BT_BYTES)             // 78381056

typedef __attribute__((ext_vector_type(8))) short bf16x8;
typedef __attribute__((ext_vector_type(4))) float f32x4;
typedef __attribute__((ext_vector_type(16))) float f32x16;

__device__ inline unsigned int bf16b(float f) {
  union { __hip_bfloat16 h; unsigned short u; } cv;
  cv.h = __float2bfloat16(f);
  return (unsigned int)cv.u;
}

__device__ __forceinline__ void gload_lds16(const void* g, void* l) {
  __builtin_amdgcn_global_load_lds(
      (const __attribute__((address_space(1))) unsigned int*)g,
      (__attribute__((address_space(3))) unsigned int*)l, 16, 0, 0);
}

// ---------------- pre-pass: x fp32->bf16 ----------------
#define XCVT_BLOCKS 16384   // 16384*256*8 = 33554432 floats
__global__ __launch_bounds__(256)
void xcvt_kernel(const float* __restrict__ X, unsigned short* __restrict__ Xbf) {
  const size_t i8 = ((size_t)blockIdx.x * 256 + threadIdx.x) * 8;
  float4 a = *(const float4*)(X + i8);
  float4 c = *(const float4*)(X + i8 + 4);
  uint4 o;
  o.x = bf16b(a.x) | (bf16b(a.y) << 16);
  o.y = bf16b(a.z) | (bf16b(a.w) << 16);
  o.z = bf16b(c.x) | (bf16b(c.y) << 16);
  o.w = bf16b(c.z) | (bf16b(c.w) << 16);
  *(uint4*)(Xbf + i8) = o;
}

// ---------------- pre-pass: B k-major PAIRED packed image ----------------
// Image dword index within bn: kt*2048 + ks*256 + g*64 + (row&31)*2 + ((row>>5)&1)
// where g = row>>6 (64-col group), pair p selects col (g*64 + p*32 + l31).
// Each dword = 16 weights (k = kt*128+ks*16..+15) of W-row n = bn*256+row.
#define BRE_BLOCKS 1376     // 1376*256 = 352256 = 43*32*256 (bn,kt,row)
__global__ __launch_bounds__(256)
void breorder_kernel(const int* __restrict__ PW, unsigned char* __restrict__ Bt) {
  const int ti = blockIdx.x * 256 + threadIdx.x;
  const int row = ti & 255;
  const int kt  = (ti >> 8) & 31;
  const int bn  = ti >> 13;
  const int* src = PW + (size_t)(bn * 256 + row) * (K_DIM / 4) + kt * 32;
  unsigned* dst = (unsigned*)Bt + (size_t)bn * 65536 + kt * 2048 +
                  (row >> 6) * 64 + (row & 31) * 2 + ((row >> 5) & 1);
#pragma unroll
  for (int ks = 0; ks < 8; ++ks) {
    int4 v = *(const int4*)(src + ks * 4);
    dst[ks * 256] = ((unsigned)v.x & 255u) | (((unsigned)v.y & 255u) << 8) |
                    (((unsigned)v.z & 255u) << 16) | (((unsigned)v.w & 255u) << 24);
  }
}

// ---------------- main: 128x256 block, 4 waves of 64x128, BK=128 dbuf, 32x32 MFMA
__global__ __launch_bounds__(256, 2)
void qlin_mm32b_kernel(const unsigned short* __restrict__ Xbf,
                       const unsigned char* __restrict__ Bt,
                       const float* __restrict__ SC, float* __restrict__ OUT) {
  __shared__ unsigned short As[2][2][8192];  // [buf][khalf][128 x 64 bf16] = 64 KB
  __shared__ unsigned char  Bs[2][8192];     // [buf][paired k-major image] = 16 KB

  const int tid = threadIdx.x;
  const int lane = tid & 63;
  const int w = tid >> 6;
  const int wm = w >> 1;      // 0..1 (M half: 64 rows)
  const int wn2 = w & 1;      // 0..1 (N half: 128 cols)

  const int wg = blockIdx.x;
  const int swz = (wg & 7) * (NWG / 8) + (wg >> 3);
  const int bm = swz / NB_N;
  const int bn = swz - bm * NB_N;

  // A stage map (R7/R14/R16-verified): per khalf 4 gload_lds/thread.
  const int l3 = lane >> 3;
  const char* ab0 = (const char*)Xbf +
      (size_t)(bm * BM + w * 32 + l3) * (K_DIM * 2) + ((lane & 7) ^ l3) * 16;
  // B stage: linear copy of paired image, wave w covers bytes w*2048..+2047.
  const char* bimg = (const char*)Bt + (size_t)(bn * KT32) * 8192;

  // 10 loads per STAGE (8 A + 2 B)
#define STAGE(IDX, KT_) do {                                                   \
    _Pragma("unroll")                                                          \
    for (int h = 0; h < 2; ++h) {                                              \
      unsigned short* ad_ = &As[IDX][h][w * 2048];                             \
      const char* as_ = ab0 + (KT_) * 256 + h * 128;                           \
      gload_lds16(as_,           ad_);                                         \
      gload_lds16(as_ + 65536,   ad_ + 512);                                   \
      gload_lds16(as_ + 131072,  ad_ + 1024);                                  \
      gload_lds16(as_ + 196608,  ad_ + 1536);                                  \
    }                                                                          \
    const char* bs_ = bimg + (size_t)(KT_) * 8192 + w * 2048 + lane * 16;      \
    unsigned char* bd_ = &Bs[IDX][w * 2048];                                   \
    gload_lds16(bs_,          bd_);                                            \
    gload_lds16(bs_ + 1024,   bd_ + 1024);                                     \
  } while (0)

  f32x16 acc[2][4];
#pragma unroll
  for (int i = 0; i < 2; ++i)
#pragma unroll
    for (int j = 0; j < 4; ++j)
#pragma unroll
      for (int r = 0; r < 16; ++r) acc[i][j][r] = 0.f;

  // fragment geometry (32x32x16): A row = lane&31, k = (lane>>5)*8 + e.
  const int l31 = lane & 31;
  const int l5 = lane >> 5;
  const int a7 = lane & 7;
  const unsigned hoff = (unsigned)l5 * 16;
  const int arow_b = (wm * 64 + l31) * 128;   // + mt*4096 + chunk

#define COMPUTE(B_) do {                                                        \
    _Pragma("unroll")                                                           \
    for (int ks = 0; ks < 8; ++ks) {                                            \
      const int kh_ = ks >> 2;                                                  \
      const int kl_ = ks & 3;                                                   \
      const char* asb_ = (const char*)&As[B_][kh_][0];                          \
      const unsigned char* bsb_ = &Bs[B_][0];                                   \
      bf16x8 af[2];                                                             \
      _Pragma("unroll")                                                         \
      for (int mt = 0; mt < 2; ++mt)                                            \
        af[mt] = *(const bf16x8*)(asb_ + arow_b + mt * 4096 +                   \
                                  (((kl_ * 2 + l5) ^ a7) << 4));                \
      bf16x8 bfr[4];                                                            \
      _Pragma("unroll")                                                         \
      for (int gg = 0; gg < 2; ++gg) {                                          \
        const uint2 dd = *(const uint2*)(bsb_ + ks * 1024 +                     \
                                         (wn2 * 2 + gg) * 256 + l31 * 8);       \
        _Pragma("unroll")                                                       \
        for (int p = 0; p < 2; ++p) {                                           \
          const unsigned d = p ? dd.y : dd.x;                                   \
          const unsigned w16 = (d >> hoff) & 0xFFFFu;                           \
          const unsigned u = w16 | (w16 << 14);                                 \
          union { uint4 s; bf16x8 v; } t;                                       \
          t.s.x = ((u << 14) & 0xC000C000u) + 0x40004000u;                      \
          t.s.y = ((u << 10) & 0xC000C000u) + 0x40004000u;                      \
          t.s.z = ((u << 6)  & 0xC000C000u) + 0x40004000u;                      \
          t.s.w = ((u << 2)  & 0xC000C000u) + 0x40004000u;                      \
          bfr[gg * 2 + p] = t.v;                                                \
        }                                                                       \
      }                                                                         \
      _Pragma("unroll")                                                         \
      for (int mt = 0; mt < 2; ++mt)                                            \
        _Pragma("unroll")                                                       \
        for (int nt = 0; nt < 4; ++nt)                                          \
          acc[mt][nt] = __builtin_amdgcn_mfma_f32_32x32x16_bf16(                \
              af[mt], bfr[nt], acc[mt][nt], 0, 0, 0);                           \
    }                                                                           \
  } while (0)

  // ---- main loop: dbuf, counted vmcnt(10), 2 raw barriers per kt ----
  STAGE(0, 0);                                   // 10 loads in flight
  int cur = 0;
  for (int kt = 0; kt < KT32 - 1; ++kt) {
    STAGE(cur ^ 1, kt + 1);                      // 20 in flight
    asm volatile("s_waitcnt vmcnt(10)" ::: "memory");  // cur's 10 done; nxt's fly
    __builtin_amdgcn_s_barrier();                // all waves: cur ready
    COMPUTE(cur);
    asm volatile("s_waitcnt lgkmcnt(0)" ::: "memory"); // my reads of cur done
    __builtin_amdgcn_s_barrier();                // all waves done reading cur
    cur ^= 1;
  }
  asm volatile("s_waitcnt vmcnt(0)" ::: "memory");     // tail: last buffer
  __builtin_amdgcn_s_barrier();
  COMPUTE(cur);
#undef STAGE
#undef COMPUTE

  // epilogue: acc * (-0.5*scale[col]); C/D (m74/m101):
  // col = lane&31, row = (reg&3) + 8*(reg>>2) + 4*(lane>>5)
#pragma unroll
  for (int nt = 0; nt < 4; ++nt) {
    const int gc = bn * BN + wn2 * 128 + nt * 32 + l31;
    const float s = -0.5f * SC[gc];
#pragma unroll
    for (int mt = 0; mt < 2; ++mt) {
      const int gr0 = bm * BM + wm * 64 + mt * 32 + 4 * l5;
#pragma unroll
      for (int reg = 0; reg < 16; ++reg) {
        const int row = gr0 + (reg & 3) + 8 * (reg >> 2);
        OUT[(size_t)row * N_DIM + gc] = acc[mt][nt][reg] * s;
      }
    }
  }
}

// ---------------- fallback: R5 fused kernel (ws too small) ----------
#define BSTRIDE 20
__global__ __launch_bounds__(256, 2)
void qlin_fused_kernel(const float* __restrict__ X, const int* __restrict__ PW,
                       const float* __restrict__ SC, float* __restrict__ OUT) {
  __shared__ unsigned short Asf[128 * 64];
  __shared__ unsigned char Bp[256 * BSTRIDE];

  const int tid = threadIdx.x;
  const int wg = blockIdx.x;
  const int swz = (wg & 7) * (NWG / 8) + (wg >> 3);
  const int bm = swz / NB_N;
  const int bn = swz - bm * NB_N;

  const int lane = tid & 63;
  const int wave = tid >> 6;
  const int wr = wave >> 1;
  const int wc = wave & 1;

  const int arow = tid >> 3;
  const int ac8  = tid & 7;
  const float* xptr = X + (size_t)(bm * 128 + arow) * K_DIM + ac8 * 8;
  const unsigned int aswz = ((unsigned)arow & 7u) << 4;

  const int bc  = tid & 3;
  const int br0 = tid >> 2;
  const int* pwptr = PW + (size_t)(bn * 256 + br0) * (K_DIM / 4) + bc * 4;
  const int bwoff = (bc & 1) * 8 + (bc >> 1) * 2;

  f32x4 acc[4][8];
#pragma unroll
  for (int i = 0; i < 4; ++i)
#pragma unroll
    for (int j = 0; j < 8; ++j) acc[i][j] = (f32x4){0.f, 0.f, 0.f, 0.f};

  float4 av[4][2];
  int4 bv[4];
#pragma unroll
  for (int j = 0; j < 4; ++j) {
    av[j][0] = *(const float4*)(xptr + (size_t)(32 * j) * K_DIM);
    av[j][1] = *(const float4*)(xptr + (size_t)(32 * j) * K_DIM + 4);
  }
#pragma unroll
  for (int j = 0; j < 4; ++j)
    bv[j] = *(const int4*)(pwptr + (size_t)(64 * j) * (K_DIM / 4));

  for (int kt = 0; kt < 64; ++kt) {
    __syncthreads();
#pragma unroll
    for (int j = 0; j < 4; ++j) {
      uint4 wv;
      wv.x = bf16b(av[j][0].x) | (bf16b(av[j][0].y) << 16);
      wv.y = bf16b(av[j][0].z) | (bf16b(av[j][0].w) << 16);
      wv.z = bf16b(av[j][1].x) | (bf16b(av[j][1].y) << 16);
      wv.w = bf16b(av[j][1].z) | (bf16b(av[j][1].w) << 16);
      *(uint4*)((char*)Asf + (arow + 32 * j) * 128 + (((unsigned)ac8 * 16u) ^ aswz)) = wv;
    }
#pragma unroll
    for (int j = 0; j < 4; ++j) {
      const unsigned int ulo = ((unsigned)bv[j].x & 255u) | (((unsigned)bv[j].y & 255u) << 8);
      const unsigned int uhi = ((unsigned)bv[j].z & 255u) | (((unsigned)bv[j].w & 255u) << 8);
      unsigned char* dst = Bp + (br0 + 64 * j) * BSTRIDE + bwoff;
      *(unsigned short*)(dst)     = (unsigned short)ulo;
      *(unsigned short*)(dst + 4) = (unsigned short)uhi;
    }
    __syncthreads();

    if (kt + 1 < 64) {
#pragma unroll
      for (int j = 0; j < 4; ++j) {
        av[j][0] = *(const float4*)(xptr + (kt + 1) * 64 + (size_t)(32 * j) * K_DIM);
        av[j][1] = *(const float4*)(xptr + (kt + 1) * 64 + (size_t)(32 * j) * K_DIM + 4);
      }
#pragma unroll
      for (int j = 0; j < 4; ++j)
        bv[j] = *(const int4*)(pwptr + (kt + 1) * 16 + (size_t)(64 * j) * (K_DIM / 4));
    }

    const int bh = lane >> 4;
    const int bcol0 = wc * 128 + (lane & 15);
    unsigned int d[8];
#pragma unroll
    for (int n = 0; n < 8; ++n)
      d[n] = *(const unsigned int*)(Bp + (bcol0 + n * 16) * BSTRIDE + bh * 4);

    const unsigned int rswz = ((unsigned)lane & 7u) << 4;
#pragma unroll
    for (int kk = 0; kk < 2; ++kk) {
      bf16x8 af[4];
      const unsigned int coff = (((unsigned)(kk * 4 + (lane >> 4))) * 16u) ^ rswz;
#pragma unroll
      for (int m = 0; m < 4; ++m)
        af[m] = *(const bf16x8*)((const char*)Asf + (wr * 64 + m * 16 + (lane & 15)) * 128 + coff);
#pragma unroll
      for (int n = 0; n < 8; ++n) {
        const unsigned int w16 = kk ? (d[n] >> 16) : (d[n] & 0xFFFFu);
        const unsigned int u = w16 | (w16 << 14);
        union { uint4 s; bf16x8 v; } bfr;
        bfr.s.x = ((u << 14) & 0xC000C000u) + 0x40004000u;
        bfr.s.y = ((u << 10) & 0xC000C000u) + 0x40004000u;
        bfr.s.z = ((u << 6)  & 0xC000C000u) + 0x40004000u;
        bfr.s.w = ((u << 2)  & 0xC000C000u) + 0x40004000u;
#pragma unroll
        for (int m = 0; m < 4; ++m)
          acc[m][n] = __builtin_amdgcn_mfma_f32_16x16x32_bf16(af[m], bfr.v, acc[m][n], 0, 0, 0);
      }
    }
  }

  const int gc0 = bn * 256 + wc * 128 + (lane & 15);
  const int gr0 = bm * 128 + wr * 64 + ((lane >> 4) << 2);
  float sc[8];
#pragma unroll
  for (int n = 0; n < 8; ++n) sc[n] = -0.5f * SC[gc0 + n * 16];
#pragma unroll
  for (int m = 0; m < 4; ++m)
#pragma unroll
    for (int n = 0; n < 8; ++n)
#pragma unroll
      for (int r = 0; r < 4; ++r)
        OUT[(size_t)(gr0 + m * 16 + r) * N_DIM + gc0 + n * 16] = acc[m][n][r] * sc[n];
}

extern "C" void kernel_launch(void* const* d_in, const int* in_sizes, int n_in,
                              void* d_out, int out_size, void* d_ws, size_t ws_size,
                              hipStream_t stream) {
  const float* x  = (const float*)d_in[0];
  const int*   pw = (const int*)d_in[1];
  const float* sc = (const float*)d_in[2];
  float* out = (float*)d_out;
  (void)in_sizes; (void)n_in; (void)out_size;

  if (ws_size >= WS_NEED) {
    unsigned short* xbf = (unsigned short*)d_ws;
    unsigned char* bt = (unsigned char*)d_ws + XBF_BYTES;
    xcvt_kernel<<<dim3(XCVT_BLOCKS), dim3(256), 0, stream>>>(x, xbf);
    breorder_kernel<<<dim3(BRE_BLOCKS), dim3(256), 0, stream>>>(pw, bt);
    qlin_mm32b_kernel<<<dim3(NWG), dim3(256), 0, stream>>>(xbf, bt, sc, out);
  } else {
    qlin_fused_kernel<<<dim3(NWG), dim3(256), 0, stream>>>(x, pw, sc, out);
  }
}

// Round 18
// 654.436 us; speedup vs baseline: 1.0519x; 1.0519x over previous
//
#include <hip/hip_runtime.h>
#include <hip/hip_bf16.h>

// Ternary-quantized linear: out[M,N] = x[M,K] . W^T,  W[n,k] = q[n,k]*scale[n].
// R18: R16 (best: 32x32x16 MFMA, 128x256 block, 4 waves of 128x64, BK=128
//      dbuf, counted vmcnt(10), 2 raw barriers) + T5 setprio around COMPUTE
//      (2 independent blocks/CU at different kt phases = the m191 condition)
//      + prepass fused into ONE kernel (xcvt 16384 blocks + breorder 1376).
//      GEMM otherwise byte-identical to R16. Fallback = R5 fused.

#define M_DIM 8192
#define N_DIM 11008
#define K_DIM 4096
#define BM 128
#define BN 256
#define KT32 32                     // K-tiles of 128
#define NB_N 43
#define NWG 2752                    // 64*43, %8 == 0

#define XBF_BYTES ((size_t)M_DIM * K_DIM * 2)        // 67108864
#define BT_BYTES  ((size_t)N_DIM * K_DIM / 4)        // 11272192
#define WS_NEED   (XBF_BYTES + BT_BYTES)             // 78381056

typedef __attribute__((ext_vector_type(8))) short bf16x8;
typedef __attribute__((ext_vector_type(4))) float f32x4;
typedef __attribute__((ext_vector_type(16))) float f32x16;

__device__ inline unsigned int bf16b(float f) {
  union { __hip_bfloat16 h; unsigned short u; } cv;
  cv.h = __float2bfloat16(f);
  return (unsigned int)cv.u;
}

__device__ __forceinline__ void gload_lds16(const void* g, void* l) {
  __builtin_amdgcn_global_load_lds(
      (const __attribute__((address_space(1))) unsigned int*)g,
      (__attribute__((address_space(3))) unsigned int*)l, 16, 0, 0);
}

// ---------------- fused pre-pass ----------------
// blocks 0..16383: x fp32->bf16 (8 floats/thread)
// blocks 16384..17759: B k-major image (row-tile per thread)
#define XCVT_BLOCKS 16384
#define BRE_BLOCKS 1376     // 1376*256 = 352256 = 43*32*256 (bn,kt,row)
__global__ __launch_bounds__(256)
void prep_kernel(const float* __restrict__ X, const int* __restrict__ PW,
                 unsigned short* __restrict__ Xbf, unsigned char* __restrict__ Bt) {
  const int b = blockIdx.x;
  if (b < XCVT_BLOCKS) {
    const size_t i8 = ((size_t)b * 256 + threadIdx.x) * 8;
    float4 a = *(const float4*)(X + i8);
    float4 c = *(const float4*)(X + i8 + 4);
    uint4 o;
    o.x = bf16b(a.x) | (bf16b(a.y) << 16);
    o.y = bf16b(a.z) | (bf16b(a.w) << 16);
    o.z = bf16b(c.x) | (bf16b(c.y) << 16);
    o.w = bf16b(c.z) | (bf16b(c.w) << 16);
    *(uint4*)(Xbf + i8) = o;
  } else {
    const int ti = (b - XCVT_BLOCKS) * 256 + threadIdx.x;
    const int row = ti & 255;
    const int kt  = (ti >> 8) & 31;
    const int bn  = ti >> 13;
    const int* src = PW + (size_t)(bn * 256 + row) * (K_DIM / 4) + kt * 32;
    unsigned* dst = (unsigned*)Bt + (size_t)bn * 65536 + kt * 2048 + row;
#pragma unroll
    for (int ks = 0; ks < 8; ++ks) {
      int4 v = *(const int4*)(src + ks * 4);
      dst[ks * 256] = ((unsigned)v.x & 255u) | (((unsigned)v.y & 255u) << 8) |
                      (((unsigned)v.z & 255u) << 16) | (((unsigned)v.w & 255u) << 24);
    }
  }
}

// ---------------- main: 128x256 block, 4 waves of 128x64, BK=128 dbuf, 32x32 MFMA
__global__ __launch_bounds__(256, 2)
void qlin_mm32_kernel(const unsigned short* __restrict__ Xbf,
                      const unsigned char* __restrict__ Bt,
                      const float* __restrict__ SC, float* __restrict__ OUT) {
  __shared__ unsigned short As[2][2][8192];  // [buf][khalf][128 x 64 bf16] = 64 KB
  __shared__ unsigned char  Bs[2][8192];     // [buf][k-major packed image] = 16 KB

  const int tid = threadIdx.x;
  const int lane = tid & 63;
  const int w = tid >> 6;

  const int wg = blockIdx.x;
  const int swz = (wg & 7) * (NWG / 8) + (wg >> 3);
  const int bm = swz / NB_N;
  const int bn = swz - bm * NB_N;

  // A stage map (R7/R14-verified): per khalf 4 gload_lds/thread.
  // LDS byte o = w*4096 + i*1024 + lane*16 -> row = w*32+i*8+(lane>>3),
  // slot = lane&7; source chunk = slot ^ (row&7) = (lane&7)^(lane>>3).
  const int l3 = lane >> 3;
  const char* ab0 = (const char*)Xbf +
      (size_t)(bm * BM + w * 32 + l3) * (K_DIM * 2) + ((lane & 7) ^ l3) * 16;
  // B stage: linear copy of k-major image, wave w covers bytes w*2048..+2047.
  const char* bimg = (const char*)Bt + (size_t)(bn * KT32) * 8192;

  // 10 loads per STAGE (8 A + 2 B)
#define STAGE(IDX, KT_) do {                                                   \
    _Pragma("unroll")                                                          \
    for (int h = 0; h < 2; ++h) {                                              \
      unsigned short* ad_ = &As[IDX][h][w * 2048];                             \
      const char* as_ = ab0 + (KT_) * 256 + h * 128;                           \
      gload_lds16(as_,           ad_);                                         \
      gload_lds16(as_ + 65536,   ad_ + 512);                                   \
      gload_lds16(as_ + 131072,  ad_ + 1024);                                  \
      gload_lds16(as_ + 196608,  ad_ + 1536);                                  \
    }                                                                          \
    const char* bs_ = bimg + (size_t)(KT_) * 8192 + w * 2048 + lane * 16;      \
    unsigned char* bd_ = &Bs[IDX][w * 2048];                                   \
    gload_lds16(bs_,          bd_);                                            \
    gload_lds16(bs_ + 1024,   bd_ + 1024);                                     \
  } while (0)

  f32x16 acc[4][2];
#pragma unroll
  for (int i = 0; i < 4; ++i)
#pragma unroll
    for (int j = 0; j < 2; ++j)
#pragma unroll
      for (int r = 0; r < 16; ++r) acc[i][j][r] = 0.f;

  // fragment geometry (32x32x16): A row = lane&31, k = (lane>>5)*8 + e.
  const int l31 = lane & 31;
  const int l5 = lane >> 5;
  const int a7 = lane & 7;            // row&7 for A rows
  const unsigned hoff = (unsigned)l5 * 16;
  const int arow32 = l31 * 128;       // A row byte offset within khalf image

#define COMPUTE(B_) do {                                                        \
    _Pragma("unroll")                                                           \
    for (int ks = 0; ks < 8; ++ks) {                                            \
      const int kh_ = ks >> 2;                                                  \
      const int kl_ = ks & 3;                                                   \
      const char* asb_ = (const char*)&As[B_][kh_][0];                          \
      const unsigned char* bsb_ = &Bs[B_][0];                                   \
      bf16x8 af[4];                                                             \
      _Pragma("unroll")                                                         \
      for (int mt = 0; mt < 4; ++mt)                                            \
        af[mt] = *(const bf16x8*)(asb_ + mt * 4096 + arow32 +                   \
                                  (((kl_ * 2 + l5) ^ a7) << 4));                \
      bf16x8 bfr[2];                                                            \
      _Pragma("unroll")                                                         \
      for (int nt = 0; nt < 2; ++nt) {                                          \
        const unsigned d = *(const unsigned*)(bsb_ + ks * 1024 +                \
                                              (w * 64 + nt * 32 + l31) * 4);    \
        const unsigned w16 = (d >> hoff) & 0xFFFFu;                             \
        const unsigned u = w16 | (w16 << 14);                                   \
        union { uint4 s; bf16x8 v; } t;                                         \
        t.s.x = ((u << 14) & 0xC000C000u) + 0x40004000u;                        \
        t.s.y = ((u << 10) & 0xC000C000u) + 0x40004000u;                        \
        t.s.z = ((u << 6)  & 0xC000C000u) + 0x40004000u;                        \
        t.s.w = ((u << 2)  & 0xC000C000u) + 0x40004000u;                        \
        bfr[nt] = t.v;                                                          \
      }                                                                         \
      _Pragma("unroll")                                                         \
      for (int mt = 0; mt < 4; ++mt)                                            \
        _Pragma("unroll")                                                       \
        for (int nt = 0; nt < 2; ++nt)                                          \
          acc[mt][nt] = __builtin_amdgcn_mfma_f32_32x32x16_bf16(                \
              af[mt], bfr[nt], acc[mt][nt], 0, 0, 0);                           \
    }                                                                           \
  } while (0)

  // ---- main loop: dbuf, counted vmcnt(10), 2 raw barriers per kt, T5 prio ----
  STAGE(0, 0);                                   // 10 loads in flight
  int cur = 0;
  for (int kt = 0; kt < KT32 - 1; ++kt) {
    STAGE(cur ^ 1, kt + 1);                      // 20 in flight
    asm volatile("s_waitcnt vmcnt(10)" ::: "memory");  // cur's 10 done; nxt's fly
    __builtin_amdgcn_s_barrier();                // all waves: cur ready
    __builtin_amdgcn_s_setprio(1);
    COMPUTE(cur);
    __builtin_amdgcn_s_setprio(0);
    asm volatile("s_waitcnt lgkmcnt(0)" ::: "memory"); // my reads of cur done
    __builtin_amdgcn_s_barrier();                // all waves done reading cur
    cur ^= 1;
  }
  asm volatile("s_waitcnt vmcnt(0)" ::: "memory");     // tail: last buffer
  __builtin_amdgcn_s_barrier();
  COMPUTE(cur);
#undef STAGE
#undef COMPUTE

  // epilogue: acc * (-0.5*scale[col]); C/D (m74/m101):
  // col = lane&31, row = (reg&3) + 8*(reg>>2) + 4*(lane>>5)
#pragma unroll
  for (int nt = 0; nt < 2; ++nt) {
    const int gc = bn * BN + w * 64 + nt * 32 + l31;
    const float s = -0.5f * SC[gc];
#pragma unroll
    for (int mt = 0; mt < 4; ++mt) {
      const int gr0 = bm * BM + mt * 32 + 4 * l5;
#pragma unroll
      for (int reg = 0; reg < 16; ++reg) {
        const int row = gr0 + (reg & 3) + 8 * (reg >> 2);
        OUT[(size_t)row * N_DIM + gc] = acc[mt][nt][reg] * s;
      }
    }
  }
}

// ---------------- fallback: R5 fused kernel (ws too small) ----------
#define BSTRIDE 20
__global__ __launch_bounds__(256, 2)
void qlin_fused_kernel(const float* __restrict__ X, const int* __restrict__ PW,
                       const float* __restrict__ SC, float* __restrict__ OUT) {
  __shared__ unsigned short Asf[128 * 64];
  __shared__ unsigned char Bp[256 * BSTRIDE];

  const int tid = threadIdx.x;
  const int wg = blockIdx.x;
  const int swz = (wg & 7) * (NWG / 8) + (wg >> 3);
  const int bm = swz / NB_N;
  const int bn = swz - bm * NB_N;

  const int lane = tid & 63;
  const int wave = tid >> 6;
  const int wr = wave >> 1;
  const int wc = wave & 1;

  const int arow = tid >> 3;
  const int ac8  = tid & 7;
  const float* xptr = X + (size_t)(bm * 128 + arow) * K_DIM + ac8 * 8;
  const unsigned int aswz = ((unsigned)arow & 7u) << 4;

  const int bc  = tid & 3;
  const int br0 = tid >> 2;
  const int* pwptr = PW + (size_t)(bn * 256 + br0) * (K_DIM / 4) + bc * 4;
  const int bwoff = (bc & 1) * 8 + (bc >> 1) * 2;

  f32x4 acc[4][8];
#pragma unroll
  for (int i = 0; i < 4; ++i)
#pragma unroll
    for (int j = 0; j < 8; ++j) acc[i][j] = (f32x4){0.f, 0.f, 0.f, 0.f};

  float4 av[4][2];
  int4 bv[4];
#pragma unroll
  for (int j = 0; j < 4; ++j) {
    av[j][0] = *(const float4*)(xptr + (size_t)(32 * j) * K_DIM);
    av[j][1] = *(const float4*)(xptr + (size_t)(32 * j) * K_DIM + 4);
  }
#pragma unroll
  for (int j = 0; j < 4; ++j)
    bv[j] = *(const int4*)(pwptr + (size_t)(64 * j) * (K_DIM / 4));

  for (int kt = 0; kt < 64; ++kt) {
    __syncthreads();
#pragma unroll
    for (int j = 0; j < 4; ++j) {
      uint4 wv;
      wv.x = bf16b(av[j][0].x) | (bf16b(av[j][0].y) << 16);
      wv.y = bf16b(av[j][0].z) | (bf16b(av[j][0].w) << 16);
      wv.z = bf16b(av[j][1].x) | (bf16b(av[j][1].y) << 16);
      wv.w = bf16b(av[j][1].z) | (bf16b(av[j][1].w) << 16);
      *(uint4*)((char*)Asf + (arow + 32 * j) * 128 + (((unsigned)ac8 * 16u) ^ aswz)) = wv;
    }
#pragma unroll
    for (int j = 0; j < 4; ++j) {
      const unsigned int ulo = ((unsigned)bv[j].x & 255u) | (((unsigned)bv[j].y & 255u) << 8);
      const unsigned int uhi = ((unsigned)bv[j].z & 255u) | (((unsigned)bv[j].w & 255u) << 8);
      unsigned char* dst = Bp + (br0 + 64 * j) * BSTRIDE + bwoff;
      *(unsigned short*)(dst)     = (unsigned short)ulo;
      *(unsigned short*)(dst + 4) = (unsigned short)uhi;
    }
    __syncthreads();

    if (kt + 1 < 64) {
#pragma unroll
      for (int j = 0; j < 4; ++j) {
        av[j][0] = *(const float4*)(xptr + (kt + 1) * 64 + (size_t)(32 * j) * K_DIM);
        av[j][1] = *(const float4*)(xptr + (kt + 1) * 64 + (size_t)(32 * j) * K_DIM + 4);
      }
#pragma unroll
      for (int j = 0; j < 4; ++j)
        bv[j] = *(const int4*)(pwptr + (kt + 1) * 16 + (size_t)(64 * j) * (K_DIM / 4));
    }

    const int bh = lane >> 4;
    const int bcol0 = wc * 128 + (lane & 15);
    unsigned int d[8];
#pragma unroll
    for (int n = 0; n < 8; ++n)
      d[n] = *(const unsigned int*)(Bp + (bcol0 + n * 16) * BSTRIDE + bh * 4);

    const unsigned int rswz = ((unsigned)lane & 7u) << 4;
#pragma unroll
    for (int kk = 0; kk < 2; ++kk) {
      bf16x8 af[4];
      const unsigned int coff = (((unsigned)(kk * 4 + (lane >> 4))) * 16u) ^ rswz;
#pragma unroll
      for (int m = 0; m < 4; ++m)
        af[m] = *(const bf16x8*)((const char*)Asf + (wr * 64 + m * 16 + (lane & 15)) * 128 + coff);
#pragma unroll
      for (int n = 0; n < 8; ++n) {
        const unsigned int w16 = kk ? (d[n] >> 16) : (d[n] & 0xFFFFu);
        const unsigned int u = w16 | (w16 << 14);
        union { uint4 s; bf16x8 v; } bfr;
        bfr.s.x = ((u << 14) & 0xC000C000u) + 0x40004000u;
        bfr.s.y = ((u << 10) & 0xC000C000u) + 0x40004000u;
        bfr.s.z = ((u << 6)  & 0xC000C000u) + 0x40004000u;
        bfr.s.w = ((u << 2)  & 0xC000C000u) + 0x40004000u;
#pragma unroll
        for (int m = 0; m < 4; ++m)
          acc[m][n] = __builtin_amdgcn_mfma_f32_16x16x32_bf16(af[m], bfr.v, acc[m][n], 0, 0, 0);
      }
    }
  }

  const int gc0 = bn * 256 + wc * 128 + (lane & 15);
  const int gr0 = bm * 128 + wr * 64 + ((lane >> 4) << 2);
  float sc[8];
#pragma unroll
  for (int n = 0; n < 8; ++n) sc[n] = -0.5f * SC[gc0 + n * 16];
#pragma unroll
  for (int m = 0; m < 4; ++m)
#pragma unroll
    for (int n = 0; n < 8; ++n)
#pragma unroll
      for (int r = 0; r < 4; ++r)
        OUT[(size_t)(gr0 + m * 16 + r) * N_DIM + gc0 + n * 16] = acc[m][n][r] * sc[n];
}

extern "C" void kernel_launch(void* const* d_in, const int* in_sizes, int n_in,
                              void* d_out, int out_size, void* d_ws, size_t ws_size,
                              hipStream_t stream) {
  const float* x  = (const float*)d_in[0];
  const int*   pw = (const int*)d_in[1];
  const float* sc = (const float*)d_in[2];
  float* out = (float*)d_out;
  (void)in_sizes; (void)n_in; (void)out_size;

  if (ws_size >= WS_NEED) {
    unsigned short* xbf = (unsigned short*)d_ws;
    unsigned char* bt = (unsigned char*)d_ws + XBF_BYTES;
    prep_kernel<<<dim3(XCVT_BLOCKS + BRE_BLOCKS), dim3(256), 0, stream>>>(x, pw, xbf, bt);
    qlin_mm32_kernel<<<dim3(NWG), dim3(256), 0, stream>>>(xbf, bt, sc, out);
  } else {
    qlin_fused_kernel<<<dim3(NWG), dim3(256), 0, stream>>>(x, pw, sc, out);
  }
}

// Round 19
// 620.261 us; speedup vs baseline: 1.1099x; 1.0551x over previous
//
#include <hip/hip_runtime.h>
#include <hip/hip_bf16.h>

// Ternary-quantized linear: out[M,N] = x[M,K] . W^T,  W[n,k] = q[n,k]*scale[n].
// R19: revert R18's setprio (A/B showed -10%: m190's lockstep-GEMM result
//      reproduced). GEMM = byte-identical R16 (best measured: 32x32x16 MFMA,
//      128x256 block, 4 waves of 128x64, BK=128 dbuf, counted vmcnt(10),
//      2 raw barriers, no setprio). Keep R18's fused single prepass kernel.
//      Fallback = R5 fused.

#define M_DIM 8192
#define N_DIM 11008
#define K_DIM 4096
#define BM 128
#define BN 256
#define KT32 32                     // K-tiles of 128
#define NB_N 43
#define NWG 2752                    // 64*43, %8 == 0

#define XBF_BYTES ((size_t)M_DIM * K_DIM * 2)        // 67108864
#define BT_BYTES  ((size_t)N_DIM * K_DIM / 4)        // 11272192
#define WS_NEED   (XBF_BYTES + BT_BYTES)             // 78381056

typedef __attribute__((ext_vector_type(8))) short bf16x8;
typedef __attribute__((ext_vector_type(4))) float f32x4;
typedef __attribute__((ext_vector_type(16))) float f32x16;

__device__ inline unsigned int bf16b(float f) {
  union { __hip_bfloat16 h; unsigned short u; } cv;
  cv.h = __float2bfloat16(f);
  return (unsigned int)cv.u;
}

__device__ __forceinline__ void gload_lds16(const void* g, void* l) {
  __builtin_amdgcn_global_load_lds(
      (const __attribute__((address_space(1))) unsigned int*)g,
      (__attribute__((address_space(3))) unsigned int*)l, 16, 0, 0);
}

// ---------------- fused pre-pass ----------------
// blocks 0..16383: x fp32->bf16 (8 floats/thread)
// blocks 16384..17759: B k-major image (row-tile per thread)
#define XCVT_BLOCKS 16384
#define BRE_BLOCKS 1376     // 1376*256 = 352256 = 43*32*256 (bn,kt,row)
__global__ __launch_bounds__(256)
void prep_kernel(const float* __restrict__ X, const int* __restrict__ PW,
                 unsigned short* __restrict__ Xbf, unsigned char* __restrict__ Bt) {
  const int b = blockIdx.x;
  if (b < XCVT_BLOCKS) {
    const size_t i8 = ((size_t)b * 256 + threadIdx.x) * 8;
    float4 a = *(const float4*)(X + i8);
    float4 c = *(const float4*)(X + i8 + 4);
    uint4 o;
    o.x = bf16b(a.x) | (bf16b(a.y) << 16);
    o.y = bf16b(a.z) | (bf16b(a.w) << 16);
    o.z = bf16b(c.x) | (bf16b(c.y) << 16);
    o.w = bf16b(c.z) | (bf16b(c.w) << 16);
    *(uint4*)(Xbf + i8) = o;
  } else {
    const int ti = (b - XCVT_BLOCKS) * 256 + threadIdx.x;
    const int row = ti & 255;
    const int kt  = (ti >> 8) & 31;
    const int bn  = ti >> 13;
    const int* src = PW + (size_t)(bn * 256 + row) * (K_DIM / 4) + kt * 32;
    unsigned* dst = (unsigned*)Bt + (size_t)bn * 65536 + kt * 2048 + row;
#pragma unroll
    for (int ks = 0; ks < 8; ++ks) {
      int4 v = *(const int4*)(src + ks * 4);
      dst[ks * 256] = ((unsigned)v.x & 255u) | (((unsigned)v.y & 255u) << 8) |
                      (((unsigned)v.z & 255u) << 16) | (((unsigned)v.w & 255u) << 24);
    }
  }
}

// ---------------- main: 128x256 block, 4 waves of 128x64, BK=128 dbuf, 32x32 MFMA
__global__ __launch_bounds__(256, 2)
void qlin_mm32_kernel(const unsigned short* __restrict__ Xbf,
                      const unsigned char* __restrict__ Bt,
                      const float* __restrict__ SC, float* __restrict__ OUT) {
  __shared__ unsigned short As[2][2][8192];  // [buf][khalf][128 x 64 bf16] = 64 KB
  __shared__ unsigned char  Bs[2][8192];     // [buf][k-major packed image] = 16 KB

  const int tid = threadIdx.x;
  const int lane = tid & 63;
  const int w = tid >> 6;

  const int wg = blockIdx.x;
  const int swz = (wg & 7) * (NWG / 8) + (wg >> 3);
  const int bm = swz / NB_N;
  const int bn = swz - bm * NB_N;

  // A stage map (R7/R14-verified): per khalf 4 gload_lds/thread.
  // LDS byte o = w*4096 + i*1024 + lane*16 -> row = w*32+i*8+(lane>>3),
  // slot = lane&7; source chunk = slot ^ (row&7) = (lane&7)^(lane>>3).
  const int l3 = lane >> 3;
  const char* ab0 = (const char*)Xbf +
      (size_t)(bm * BM + w * 32 + l3) * (K_DIM * 2) + ((lane & 7) ^ l3) * 16;
  // B stage: linear copy of k-major image, wave w covers bytes w*2048..+2047.
  const char* bimg = (const char*)Bt + (size_t)(bn * KT32) * 8192;

  // 10 loads per STAGE (8 A + 2 B)
#define STAGE(IDX, KT_) do {                                                   \
    _Pragma("unroll")                                                          \
    for (int h = 0; h < 2; ++h) {                                              \
      unsigned short* ad_ = &As[IDX][h][w * 2048];                             \
      const char* as_ = ab0 + (KT_) * 256 + h * 128;                           \
      gload_lds16(as_,           ad_);                                         \
      gload_lds16(as_ + 65536,   ad_ + 512);                                   \
      gload_lds16(as_ + 131072,  ad_ + 1024);                                  \
      gload_lds16(as_ + 196608,  ad_ + 1536);                                  \
    }                                                                          \
    const char* bs_ = bimg + (size_t)(KT_) * 8192 + w * 2048 + lane * 16;      \
    unsigned char* bd_ = &Bs[IDX][w * 2048];                                   \
    gload_lds16(bs_,          bd_);                                            \
    gload_lds16(bs_ + 1024,   bd_ + 1024);                                     \
  } while (0)

  f32x16 acc[4][2];
#pragma unroll
  for (int i = 0; i < 4; ++i)
#pragma unroll
    for (int j = 0; j < 2; ++j)
#pragma unroll
      for (int r = 0; r < 16; ++r) acc[i][j][r] = 0.f;

  // fragment geometry (32x32x16): A row = lane&31, k = (lane>>5)*8 + e.
  const int l31 = lane & 31;
  const int l5 = lane >> 5;
  const int a7 = lane & 7;            // row&7 for A rows
  const unsigned hoff = (unsigned)l5 * 16;
  const int arow32 = l31 * 128;       // A row byte offset within khalf image

#define COMPUTE(B_) do {                                                        \
    _Pragma("unroll")                                                           \
    for (int ks = 0; ks < 8; ++ks) {                                            \
      const int kh_ = ks >> 2;                                                  \
      const int kl_ = ks & 3;                                                   \
      const char* asb_ = (const char*)&As[B_][kh_][0];                          \
      const unsigned char* bsb_ = &Bs[B_][0];                                   \
      bf16x8 af[4];                                                             \
      _Pragma("unroll")                                                         \
      for (int mt = 0; mt < 4; ++mt)                                            \
        af[mt] = *(const bf16x8*)(asb_ + mt * 4096 + arow32 +                   \
                                  (((kl_ * 2 + l5) ^ a7) << 4));                \
      bf16x8 bfr[2];                                                            \
      _Pragma("unroll")                                                         \
      for (int nt = 0; nt < 2; ++nt) {                                          \
        const unsigned d = *(const unsigned*)(bsb_ + ks * 1024 +                \
                                              (w * 64 + nt * 32 + l31) * 4);    \
        const unsigned w16 = (d >> hoff) & 0xFFFFu;                             \
        const unsigned u = w16 | (w16 << 14);                                   \
        union { uint4 s; bf16x8 v; } t;                                         \
        t.s.x = ((u << 14) & 0xC000C000u) + 0x40004000u;                        \
        t.s.y = ((u << 10) & 0xC000C000u) + 0x40004000u;                        \
        t.s.z = ((u << 6)  & 0xC000C000u) + 0x40004000u;                        \
        t.s.w = ((u << 2)  & 0xC000C000u) + 0x40004000u;                        \
        bfr[nt] = t.v;                                                          \
      }                                                                         \
      _Pragma("unroll")                                                         \
      for (int mt = 0; mt < 4; ++mt)                                            \
        _Pragma("unroll")                                                       \
        for (int nt = 0; nt < 2; ++nt)                                          \
          acc[mt][nt] = __builtin_amdgcn_mfma_f32_32x32x16_bf16(                \
              af[mt], bfr[nt], acc[mt][nt], 0, 0, 0);                           \
    }                                                                           \
  } while (0)

  // ---- main loop: dbuf, counted vmcnt(10), 2 raw barriers per kt ----
  STAGE(0, 0);                                   // 10 loads in flight
  int cur = 0;
  for (int kt = 0; kt < KT32 - 1; ++kt) {
    STAGE(cur ^ 1, kt + 1);                      // 20 in flight
    asm volatile("s_waitcnt vmcnt(10)" ::: "memory");  // cur's 10 done; nxt's fly
    __builtin_amdgcn_s_barrier();                // all waves: cur ready
    COMPUTE(cur);
    asm volatile("s_waitcnt lgkmcnt(0)" ::: "memory"); // my reads of cur done
    __builtin_amdgcn_s_barrier();                // all waves done reading cur
    cur ^= 1;
  }
  asm volatile("s_waitcnt vmcnt(0)" ::: "memory");     // tail: last buffer
  __builtin_amdgcn_s_barrier();
  COMPUTE(cur);
#undef STAGE
#undef COMPUTE

  // epilogue: acc * (-0.5*scale[col]); C/D (m74/m101):
  // col = lane&31, row = (reg&3) + 8*(reg>>2) + 4*(lane>>5)
#pragma unroll
  for (int nt = 0; nt < 2; ++nt) {
    const int gc = bn * BN + w * 64 + nt * 32 + l31;
    const float s = -0.5f * SC[gc];
#pragma unroll
    for (int mt = 0; mt < 4; ++mt) {
      const int gr0 = bm * BM + mt * 32 + 4 * l5;
#pragma unroll
      for (int reg = 0; reg < 16; ++reg) {
        const int row = gr0 + (reg & 3) + 8 * (reg >> 2);
        OUT[(size_t)row * N_DIM + gc] = acc[mt][nt][reg] * s;
      }
    }
  }
}

// ---------------- fallback: R5 fused kernel (ws too small) ----------
#define BSTRIDE 20
__global__ __launch_bounds__(256, 2)
void qlin_fused_kernel(const float* __restrict__ X, const int* __restrict__ PW,
                       const float* __restrict__ SC, float* __restrict__ OUT) {
  __shared__ unsigned short Asf[128 * 64];
  __shared__ unsigned char Bp[256 * BSTRIDE];

  const int tid = threadIdx.x;
  const int wg = blockIdx.x;
  const int swz = (wg & 7) * (NWG / 8) + (wg >> 3);
  const int bm = swz / NB_N;
  const int bn = swz - bm * NB_N;

  const int lane = tid & 63;
  const int wave = tid >> 6;
  const int wr = wave >> 1;
  const int wc = wave & 1;

  const int arow = tid >> 3;
  const int ac8  = tid & 7;
  const float* xptr = X + (size_t)(bm * 128 + arow) * K_DIM + ac8 * 8;
  const unsigned int aswz = ((unsigned)arow & 7u) << 4;

  const int bc  = tid & 3;
  const int br0 = tid >> 2;
  const int* pwptr = PW + (size_t)(bn * 256 + br0) * (K_DIM / 4) + bc * 4;
  const int bwoff = (bc & 1) * 8 + (bc >> 1) * 2;

  f32x4 acc[4][8];
#pragma unroll
  for (int i = 0; i < 4; ++i)
#pragma unroll
    for (int j = 0; j < 8; ++j) acc[i][j] = (f32x4){0.f, 0.f, 0.f, 0.f};

  float4 av[4][2];
  int4 bv[4];
#pragma unroll
  for (int j = 0; j < 4; ++j) {
    av[j][0] = *(const float4*)(xptr + (size_t)(32 * j) * K_DIM);
    av[j][1] = *(const float4*)(xptr + (size_t)(32 * j) * K_DIM + 4);
  }
#pragma unroll
  for (int j = 0; j < 4; ++j)
    bv[j] = *(const int4*)(pwptr + (size_t)(64 * j) * (K_DIM / 4));

  for (int kt = 0; kt < 64; ++kt) {
    __syncthreads();
#pragma unroll
    for (int j = 0; j < 4; ++j) {
      uint4 wv;
      wv.x = bf16b(av[j][0].x) | (bf16b(av[j][0].y) << 16);
      wv.y = bf16b(av[j][0].z) | (bf16b(av[j][0].w) << 16);
      wv.z = bf16b(av[j][1].x) | (bf16b(av[j][1].y) << 16);
      wv.w = bf16b(av[j][1].z) | (bf16b(av[j][1].w) << 16);
      *(uint4*)((char*)Asf + (arow + 32 * j) * 128 + (((unsigned)ac8 * 16u) ^ aswz)) = wv;
    }
#pragma unroll
    for (int j = 0; j < 4; ++j) {
      const unsigned int ulo = ((unsigned)bv[j].x & 255u) | (((unsigned)bv[j].y & 255u) << 8);
      const unsigned int uhi = ((unsigned)bv[j].z & 255u) | (((unsigned)bv[j].w & 255u) << 8);
      unsigned char* dst = Bp + (br0 + 64 * j) * BSTRIDE + bwoff;
      *(unsigned short*)(dst)     = (unsigned short)ulo;
      *(unsigned short*)(dst + 4) = (unsigned short)uhi;
    }
    __syncthreads();

    if (kt + 1 < 64) {
#pragma unroll
      for (int j = 0; j < 4; ++j) {
        av[j][0] = *(const float4*)(xptr + (kt + 1) * 64 + (size_t)(32 * j) * K_DIM);
        av[j][1] = *(const float4*)(xptr + (kt + 1) * 64 + (size_t)(32 * j) * K_DIM + 4);
      }
#pragma unroll
      for (int j = 0; j < 4; ++j)
        bv[j] = *(const int4*)(pwptr + (kt + 1) * 16 + (size_t)(64 * j) * (K_DIM / 4));
    }

    const int bh = lane >> 4;
    const int bcol0 = wc * 128 + (lane & 15);
    unsigned int d[8];
#pragma unroll
    for (int n = 0; n < 8; ++n)
      d[n] = *(const unsigned int*)(Bp + (bcol0 + n * 16) * BSTRIDE + bh * 4);

    const unsigned int rswz = ((unsigned)lane & 7u) << 4;
#pragma unroll
    for (int kk = 0; kk < 2; ++kk) {
      bf16x8 af[4];
      const unsigned int coff = (((unsigned)(kk * 4 + (lane >> 4))) * 16u) ^ rswz;
#pragma unroll
      for (int m = 0; m < 4; ++m)
        af[m] = *(const bf16x8*)((const char*)Asf + (wr * 64 + m * 16 + (lane & 15)) * 128 + coff);
#pragma unroll
      for (int n = 0; n < 8; ++n) {
        const unsigned int w16 = kk ? (d[n] >> 16) : (d[n] & 0xFFFFu);
        const unsigned int u = w16 | (w16 << 14);
        union { uint4 s; bf16x8 v; } bfr;
        bfr.s.x = ((u << 14) & 0xC000C000u) + 0x40004000u;
        bfr.s.y = ((u << 10) & 0xC000C000u) + 0x40004000u;
        bfr.s.z = ((u << 6)  & 0xC000C000u) + 0x40004000u;
        bfr.s.w = ((u << 2)  & 0xC000C000u) + 0x40004000u;
#pragma unroll
        for (int m = 0; m < 4; ++m)
          acc[m][n] = __builtin_amdgcn_mfma_f32_16x16x32_bf16(af[m], bfr.v, acc[m][n], 0, 0, 0);
      }
    }
  }

  const int gc0 = bn * 256 + wc * 128 + (lane & 15);
  const int gr0 = bm * 128 + wr * 64 + ((lane >> 4) << 2);
  float sc[8];
#pragma unroll
  for (int n = 0; n < 8; ++n) sc[n] = -0.5f * SC[gc0 + n * 16];
#pragma unroll
  for (int m = 0; m < 4; ++m)
#pragma unroll
    for (int n = 0; n < 8; ++n)
#pragma unroll
      for (int r = 0; r < 4; ++r)
        OUT[(size_t)(gr0 + m * 16 + r) * N_DIM + gc0 + n * 16] = acc[m][n][r] * sc[n];
}

extern "C" void kernel_launch(void* const* d_in, const int* in_sizes, int n_in,
                              void* d_out, int out_size, void* d_ws, size_t ws_size,
                              hipStream_t stream) {
  const float* x  = (const float*)d_in[0];
  const int*   pw = (const int*)d_in[1];
  const float* sc = (const float*)d_in[2];
  float* out = (float*)d_out;
  (void)in_sizes; (void)n_in; (void)out_size;

  if (ws_size >= WS_NEED) {
    unsigned short* xbf = (unsigned short*)d_ws;
    unsigned char* bt = (unsigned char*)d_ws + XBF_BYTES;
    prep_kernel<<<dim3(XCVT_BLOCKS + BRE_BLOCKS), dim3(256), 0, stream>>>(x, pw, xbf, bt);
    qlin_mm32_kernel<<<dim3(NWG), dim3(256), 0, stream>>>(xbf, bt, sc, out);
  } else {
    qlin_fused_kernel<<<dim3(NWG), dim3(256), 0, stream>>>(x, pw, sc, out);
  }
}